// Round 6
// baseline (442.244 us; speedup 1.0000x reference)
//
#include <hip/hip_runtime.h>
#include <stdint.h>

typedef unsigned short u16;
typedef __attribute__((ext_vector_type(8))) short short8;
typedef __attribute__((ext_vector_type(4))) short short4v;
typedef __attribute__((ext_vector_type(4))) float f32x4;

#define MFMA32(a, b, c) __builtin_amdgcn_mfma_f32_16x16x32_bf16(a, b, c, 0, 0, 0)

#if __has_builtin(__builtin_amdgcn_exp2f)
#define EXP2F(x) __builtin_amdgcn_exp2f(x)
#else
#define EXP2F(x) exp2f(x)   // host-pass fallback only
#endif

// sched_group_barrier masks: MFMA=0x8, VALU=0x2 (|0x400 TRANS), DS_READ=0x100
#define SGB(mask, n) __builtin_amdgcn_sched_group_barrier((mask), (n), 0)

// async global->LDS DMA, 16B per lane; dst must be base+lane*16 contiguous per wave
#define ASYNC16(G, L)                                                            \
    __builtin_amdgcn_global_load_lds((const __attribute__((address_space(1))) void*)(const void*)(G), \
                                     (__attribute__((address_space(3))) void*)(void*)(L), 16, 0, 0)

__device__ __forceinline__ u16 f2bf(float f) {
    union { float f; uint32_t u; } c; c.f = f;
    uint32_t r = (c.u + 0x7fffu + ((c.u >> 16) & 1u)) >> 16;
    return (u16)r;
}

// ---------------- convert X (fp32 -> bf16) ----------------
__global__ __launch_bounds__(256) void k_convert_x(const float* __restrict__ X, u16* __restrict__ Xb) {
    int idx = blockIdx.x * 256 + threadIdx.x;
    float4 v = ((const float4*)X)[idx];
    union { u16 s[4]; uint2 v; } u;
    u.s[0] = f2bf(v.x); u.s[1] = f2bf(v.y); u.s[2] = f2bf(v.z); u.s[3] = f2bf(v.w);
    ((uint2*)Xb)[idx] = u.v;
}

// ---------------- convert + transpose the 4 weight matrices -> W^T bf16 (n-major) ----------------
__global__ __launch_bounds__(256) void k_convert_w(const float* __restrict__ W0, const float* __restrict__ W1,
                                                   const float* __restrict__ W2, const float* __restrict__ W3,
                                                   u16* __restrict__ Wt) {
    __shared__ u16 T[64][72];
    const float* W = (blockIdx.z == 0) ? W0 : (blockIdx.z == 1) ? W1 : (blockIdx.z == 2) ? W2 : W3;
    int k0 = blockIdx.x * 64, n0 = blockIdx.y * 64;
    int t = threadIdx.x;
    for (int i = 0; i < 4; i++) {
        int id = t + i * 256;
        int row = id >> 4, c4 = (id & 15) * 4;
        float4 v = *(const float4*)(W + (size_t)(k0 + row) * 512 + n0 + c4);
        union { u16 s[4]; uint2 v; } u;
        u.s[0] = f2bf(v.x); u.s[1] = f2bf(v.y); u.s[2] = f2bf(v.z); u.s[3] = f2bf(v.w);
        *(uint2*)&T[row][c4] = u.v;
    }
    __syncthreads();
    u16* O = Wt + (size_t)blockIdx.z * 512 * 512;
    for (int i = 0; i < 2; i++) {
        int id = t + i * 256;
        int row = id >> 3, c8 = (id & 7) * 8;
        union { u16 s[8]; uint4 v; } tmp;
        for (int j = 0; j < 8; j++) tmp.s[j] = T[c8 + j][row];
        *(uint4*)(O + (size_t)(n0 + row) * 512 + k0 + c8) = tmp.v;
    }
}

// ---------------- QKV projection GEMM ----------------
__global__ __launch_bounds__(256) void k_gemm_qkv(const u16* __restrict__ X, const u16* __restrict__ Wt,
                                                  u16* __restrict__ Q, u16* __restrict__ K, u16* __restrict__ V) {
    __shared__ u16 As[128][40];
    __shared__ u16 Bs[128][40];
    const int t = threadIdx.x;
    const int wave = t >> 6, lane = t & 63, quad = lane >> 4, l16 = lane & 15;
    const int wm = (wave >> 1) * 64, wn = (wave & 1) * 64;
    const int m0 = blockIdx.x * 128, n0 = blockIdx.y * 128;
    const u16* Bt = Wt + (size_t)blockIdx.z * 262144;
    const f32x4 fz = {0.f, 0.f, 0.f, 0.f};
    f32x4 acc[4][4];
    for (int i = 0; i < 4; i++) for (int j = 0; j < 4; j++) acc[i][j] = fz;
    for (int k0 = 0; k0 < 512; k0 += 32) {
        __syncthreads();
        for (int i = 0; i < 2; i++) {
            int id = t + i * 256;
            int row = id >> 2, c8 = (id & 3) * 8;
            *(uint4*)&As[row][c8] = *(const uint4*)(X + (size_t)(m0 + row) * 512 + k0 + c8);
            *(uint4*)&Bs[row][c8] = *(const uint4*)(Bt + (size_t)(n0 + row) * 512 + k0 + c8);
        }
        __syncthreads();
        short8 af[4], bf[4];
        for (int mt = 0; mt < 4; mt++) af[mt] = *(const short8*)&As[wm + mt * 16 + l16][quad * 8];
        for (int nt = 0; nt < 4; nt++) bf[nt] = *(const short8*)&Bs[wn + nt * 16 + l16][quad * 8];
        for (int mt = 0; mt < 4; mt++)
            for (int nt = 0; nt < 4; nt++)
                acc[mt][nt] = MFMA32(af[mt], bf[nt], acc[mt][nt]);
    }
    const float scale = (blockIdx.z == 0) ? 0.18033688011112042f : 1.0f;   // (1/8)*log2(e) for Q
    u16* Out = (blockIdx.z == 0) ? Q : (blockIdx.z == 1) ? K : V;
    for (int mt = 0; mt < 4; mt++)
        for (int nt = 0; nt < 4; nt++)
            for (int r = 0; r < 4; r++) {
                int m = m0 + wm + mt * 16 + quad * 4 + r;
                int n = n0 + wn + nt * 16 + l16;
                int b = m >> 13, s = m & 8191, h = n >> 6, d = n & 63;
                Out[((size_t)((b * 8 + h) * 8192 + s)) * 64 + d] = f2bf(acc[mt][nt][r] * scale);
            }
}

// ---------------- V (bh,s,d) -> Vt (bh,d,s) ----------------
__global__ __launch_bounds__(256) void k_transpose_v(const u16* __restrict__ V, u16* __restrict__ Vt) {
    __shared__ u16 T[64][72];
    int s0 = blockIdx.x * 64, bh = blockIdx.y;
    int t = threadIdx.x;
    for (int i = 0; i < 2; i++) {
        int id = t + i * 256, row = id >> 3, c8 = (id & 7) * 8;
        *(uint4*)&T[row][c8] = *(const uint4*)(V + ((size_t)bh * 8192 + s0 + row) * 64 + c8);
    }
    __syncthreads();
    for (int i = 0; i < 2; i++) {
        int id = t + i * 256, row = id >> 3, c8 = (id & 7) * 8;
        union { u16 s[8]; uint4 v; } tmp;
        for (int j = 0; j < 8; j++) tmp.s[j] = T[c8 + j][row];
        *(uint4*)(Vt + ((size_t)bh * 64 + row) * 8192 + s0 + c8) = tmp.v;
    }
}

// ---------------- flash attention: S^T orientation, shift-free softmax, BQ=256/8 waves ----------------
// R11: intra-WAVE pipe interleave. Evidence (R1/R4/R5): three different occupancy/staging configs
// all pin MfmaUtil+VALUBusy at ~101%, and 4 waves/SIMD x 1250cy serial chain = 4950cy = measured
// wall period -> resident waves execute with ~zero cross-wave overlap (convoy effect: pipe
// contention keeps every wave phase-aligned, barriers or not). Cross-wave levers are dead; the
// MFMA/trans overlap must be built into ONE wave's instruction stream.
//   Unlike R7/R8's failed 2-tile interleave (liveness explosion -> spills), the intra-tile weave
// adds ZERO liveness: all 4 score sets + pf sets are already co-live in the R1 body's exp loop.
//   phase A: QK(kg0) 8 MFMA
//   phase B: QK(kg1) 8 MFMA woven 1:~5 with exp(kg0) 38 VALU   (indep: sc(kg1) vs sc(kg0))
//   phase C: PV(kg0) 8 MFMA woven with exp(kg1)                 (indep: pf(kg0) vs sc(kg1))
//   phase D: PV(kg1) 8 MFMA
// sched_group_barrier pins the weave (MFMA=0x8, VALU|TRANS=0x402, DS_READ=0x100) so the
// scheduler can't re-clump phases. Outer structure = R1's proven best (512thr, 2-buf, 1-ahead
// prefetch, 264us). Per-phase liveness audit: <= ~112 VGPR < 128 cap (512,4).
__global__ __launch_bounds__(512, 4) void k_flash(const u16* __restrict__ Q, const u16* __restrict__ K,
                                                  const u16* __restrict__ Vt, u16* __restrict__ Attn) {
    __shared__ u16 KsAll[2][4096];   // [buf][row*64 + chunk-swizzled cols], swz(row)=(row&3)|((row&8)>>1)
    __shared__ u16 VsAll[2][4096];   // [buf][d*64 + chunk-swizzled keys],  swz(d)=d&7
    const int t = threadIdx.x;
    const int wave = t >> 6, lane = t & 63, quad = lane >> 4, l16 = lane & 15;
    const int l7 = l16 & 7;
    const int qblk = blockIdx.x, bh = blockIdx.y;
    const int b = bh >> 3, h = bh & 7;
    const int q0g = qblk * 256;
    const int mq = wave * 32;
    const u16* Qb = Q + ((size_t)bh * 8192 + q0g) * 64;
    const u16* Kb = K + (size_t)bh * 8192 * 64;
    const u16* Vb = Vt + (size_t)bh * 64 * 8192;

    // interleaved key-tile row assignment: tileA row l16 -> local key rA, tileB -> rA+4
    const int rA = ((l16 & 12) << 1) + (l16 & 3);   // 8*(l16>>2) + (l16&3)

    // DMA: 512 threads x 16B = one full 8KB tile each for K and V; thread t <-> chunk t
    const int r0 = t >> 3;
    const int x0K = ((t & 7) ^ ((r0 & 3) | ((r0 & 8) >> 1))) * 8;
    const int x0V = ((t & 7) ^ (r0 & 7)) * 8;
    const u16* gK0 = Kb + r0 * 64 + x0K;
    const u16* gV0 = Vb + (size_t)r0 * 8192 + x0V;
    u16* lK = &KsAll[0][0] + t * 8;
    u16* lV = &VsAll[0][0] + t * 8;

    auto prefetch = [&](int it, int buf) {
        ASYNC16(gK0 + it * 4096, lK + buf * 4096);
        ASYNC16(gV0 + it * 64,   lV + buf * 4096);
    };

    // Q fragments (B-operand of S^T mfma): loop-invariant
    short8 qf[2][2];
    for (int mt = 0; mt < 2; mt++)
        for (int ks = 0; ks < 2; ks++)
            qf[mt][ks] = *(const short8*)(Qb + (size_t)(mq + mt * 16 + l16) * 64 + ks * 32 + quad * 8);

    const f32x4 fz = {0.f, 0.f, 0.f, 0.f};
    f32x4 o[2][4];
    float l_i[2] = {0.f, 0.f};   // lane-local partial: sum of p over this lane's keys, q=l16
    for (int mt = 0; mt < 2; mt++) for (int nt = 0; nt < 4; nt++) o[mt][nt] = fz;

    prefetch(0, 0);

    auto body = [&](int it, int buf) {
        __syncthreads();                       // drains prefetch(it) (issued one body ago)
        if (it != 127) prefetch(it + 1, buf ^ 1);
        const u16* KsB = &KsAll[buf][0];
        const u16* VsB = &VsAll[buf][0];

        // all 8 K-fragment reads (kg0: a*, b*; kg1: c*, d*)
        const u16* Kg0A = KsB + rA * 64;
        const u16* Kg0B = Kg0A + 256;
        const u16* Kg1A = KsB + 2048 + rA * 64;
        const u16* Kg1B = Kg1A + 256;
        short8 a0 = *(const short8*)(Kg0A + ((quad) ^ l7) * 8);
        short8 a1 = *(const short8*)(Kg0A + ((4 + quad) ^ l7) * 8);
        short8 b0 = *(const short8*)(Kg0B + ((quad) ^ l7) * 8);
        short8 b1 = *(const short8*)(Kg0B + ((4 + quad) ^ l7) * 8);
        short8 c0 = *(const short8*)(Kg1A + ((quad) ^ l7) * 8);
        short8 c1 = *(const short8*)(Kg1A + ((4 + quad) ^ l7) * 8);
        short8 d0 = *(const short8*)(Kg1B + ((quad) ^ l7) * 8);
        short8 d1 = *(const short8*)(Kg1B + ((4 + quad) ^ l7) * 8);

        // ---- phase A: QK kg0 (8 MFMA) ----
        f32x4 sA00 = MFMA32(a0, qf[0][0], fz);
        f32x4 sA10 = MFMA32(a0, qf[1][0], fz);
        f32x4 sB00 = MFMA32(b0, qf[0][0], fz);
        f32x4 sB10 = MFMA32(b0, qf[1][0], fz);
        sA00 = MFMA32(a1, qf[0][1], sA00);
        sA10 = MFMA32(a1, qf[1][1], sA10);
        sB00 = MFMA32(b1, qf[0][1], sB00);
        sB10 = MFMA32(b1, qf[1][1], sB10);
        SGB(0x8, 8);

        union fu { float f; uint32_t u; };
        fu eA0, eA1, eA2, eA3, eB0, eB1, eB2, eB3;
        union pku { uint32_t u[4]; short8 s; } pk;
        short8 pf00, pf10, pf01, pf11;
        f32x4 sA01, sA11, sB01, sB11;

        // ---- phase B: QK kg1 woven with exp(kg0) ----
        sA01 = MFMA32(c0, qf[0][0], fz);
        SGB(0x8, 1);
        eA0.f = EXP2F(sA00[0]); eA1.f = EXP2F(sA00[1]); eA2.f = EXP2F(sA00[2]); eA3.f = EXP2F(sA00[3]);
        SGB(0x402, 4);
        sA11 = MFMA32(c0, qf[1][0], fz);
        SGB(0x8, 1);
        eB0.f = EXP2F(sB00[0]); eB1.f = EXP2F(sB00[1]); eB2.f = EXP2F(sB00[2]); eB3.f = EXP2F(sB00[3]);
        SGB(0x402, 4);
        sB01 = MFMA32(d0, qf[0][0], fz);
        SGB(0x8, 1);
        l_i[0] += ((eA0.f + eA1.f) + (eA2.f + eA3.f)) + ((eB0.f + eB1.f) + (eB2.f + eB3.f));
        pk.u[0] = __builtin_amdgcn_perm(eA1.u, eA0.u, 0x07060302);
        pk.u[1] = __builtin_amdgcn_perm(eA3.u, eA2.u, 0x07060302);
        pk.u[2] = __builtin_amdgcn_perm(eB1.u, eB0.u, 0x07060302);
        pk.u[3] = __builtin_amdgcn_perm(eB3.u, eB2.u, 0x07060302);
        pf00 = pk.s;
        SGB(0x402, 11);
        sB11 = MFMA32(d0, qf[1][0], fz);
        SGB(0x8, 1);
        eA0.f = EXP2F(sA10[0]); eA1.f = EXP2F(sA10[1]); eA2.f = EXP2F(sA10[2]); eA3.f = EXP2F(sA10[3]);
        SGB(0x402, 4);
        sA01 = MFMA32(c1, qf[0][1], sA01);
        SGB(0x8, 1);
        eB0.f = EXP2F(sB10[0]); eB1.f = EXP2F(sB10[1]); eB2.f = EXP2F(sB10[2]); eB3.f = EXP2F(sB10[3]);
        SGB(0x402, 4);
        sA11 = MFMA32(c1, qf[1][1], sA11);
        SGB(0x8, 1);
        l_i[1] += ((eA0.f + eA1.f) + (eA2.f + eA3.f)) + ((eB0.f + eB1.f) + (eB2.f + eB3.f));
        pk.u[0] = __builtin_amdgcn_perm(eA1.u, eA0.u, 0x07060302);
        pk.u[1] = __builtin_amdgcn_perm(eA3.u, eA2.u, 0x07060302);
        pk.u[2] = __builtin_amdgcn_perm(eB1.u, eB0.u, 0x07060302);
        pk.u[3] = __builtin_amdgcn_perm(eB3.u, eB2.u, 0x07060302);
        pf10 = pk.s;
        SGB(0x402, 11);
        sB01 = MFMA32(d1, qf[0][1], sB01);
        SGB(0x8, 1);
        sB11 = MFMA32(d1, qf[1][1], sB11);
        SGB(0x8, 1);

        // ---- phase C: PV kg0 woven with exp(kg1) ----
        short8 vf0 = *(const short8*)(VsB + 0 * 1024 + l16 * 64 + (((quad) ^ l7) * 8));
        short8 vf1 = *(const short8*)(VsB + 1 * 1024 + l16 * 64 + (((quad) ^ l7) * 8));
        short8 vf2 = *(const short8*)(VsB + 2 * 1024 + l16 * 64 + (((quad) ^ l7) * 8));
        short8 vf3 = *(const short8*)(VsB + 3 * 1024 + l16 * 64 + (((quad) ^ l7) * 8));
        SGB(0x100, 4);
        o[0][0] = MFMA32(pf00, vf0, o[0][0]);
        SGB(0x8, 1);
        eA0.f = EXP2F(sA01[0]); eA1.f = EXP2F(sA01[1]); eA2.f = EXP2F(sA01[2]); eA3.f = EXP2F(sA01[3]);
        SGB(0x402, 4);
        o[1][0] = MFMA32(pf10, vf0, o[1][0]);
        SGB(0x8, 1);
        eB0.f = EXP2F(sB01[0]); eB1.f = EXP2F(sB01[1]); eB2.f = EXP2F(sB01[2]); eB3.f = EXP2F(sB01[3]);
        SGB(0x402, 4);
        o[0][1] = MFMA32(pf00, vf1, o[0][1]);
        SGB(0x8, 1);
        l_i[0] += ((eA0.f + eA1.f) + (eA2.f + eA3.f)) + ((eB0.f + eB1.f) + (eB2.f + eB3.f));
        pk.u[0] = __builtin_amdgcn_perm(eA1.u, eA0.u, 0x07060302);
        pk.u[1] = __builtin_amdgcn_perm(eA3.u, eA2.u, 0x07060302);
        pk.u[2] = __builtin_amdgcn_perm(eB1.u, eB0.u, 0x07060302);
        pk.u[3] = __builtin_amdgcn_perm(eB3.u, eB2.u, 0x07060302);
        pf01 = pk.s;
        SGB(0x402, 11);
        o[1][1] = MFMA32(pf10, vf1, o[1][1]);
        SGB(0x8, 1);
        eA0.f = EXP2F(sA11[0]); eA1.f = EXP2F(sA11[1]); eA2.f = EXP2F(sA11[2]); eA3.f = EXP2F(sA11[3]);
        SGB(0x402, 4);
        o[0][2] = MFMA32(pf00, vf2, o[0][2]);
        SGB(0x8, 1);
        eB0.f = EXP2F(sB11[0]); eB1.f = EXP2F(sB11[1]); eB2.f = EXP2F(sB11[2]); eB3.f = EXP2F(sB11[3]);
        SGB(0x402, 4);
        o[1][2] = MFMA32(pf10, vf2, o[1][2]);
        SGB(0x8, 1);
        l_i[1] += ((eA0.f + eA1.f) + (eA2.f + eA3.f)) + ((eB0.f + eB1.f) + (eB2.f + eB3.f));
        pk.u[0] = __builtin_amdgcn_perm(eA1.u, eA0.u, 0x07060302);
        pk.u[1] = __builtin_amdgcn_perm(eA3.u, eA2.u, 0x07060302);
        pk.u[2] = __builtin_amdgcn_perm(eB1.u, eB0.u, 0x07060302);
        pk.u[3] = __builtin_amdgcn_perm(eB3.u, eB2.u, 0x07060302);
        pf11 = pk.s;
        SGB(0x402, 11);
        o[0][3] = MFMA32(pf00, vf3, o[0][3]);
        SGB(0x8, 1);
        o[1][3] = MFMA32(pf10, vf3, o[1][3]);
        SGB(0x8, 1);

        // ---- phase D: PV kg1 (8 MFMA) ----
        short8 wf0 = *(const short8*)(VsB + 0 * 1024 + l16 * 64 + (((4 + quad) ^ l7) * 8));
        short8 wf1 = *(const short8*)(VsB + 1 * 1024 + l16 * 64 + (((4 + quad) ^ l7) * 8));
        short8 wf2 = *(const short8*)(VsB + 2 * 1024 + l16 * 64 + (((4 + quad) ^ l7) * 8));
        short8 wf3 = *(const short8*)(VsB + 3 * 1024 + l16 * 64 + (((4 + quad) ^ l7) * 8));
        SGB(0x100, 4);
        o[0][0] = MFMA32(pf01, wf0, o[0][0]);
        o[1][0] = MFMA32(pf11, wf0, o[1][0]);
        o[0][1] = MFMA32(pf01, wf1, o[0][1]);
        o[1][1] = MFMA32(pf11, wf1, o[1][1]);
        o[0][2] = MFMA32(pf01, wf2, o[0][2]);
        o[1][2] = MFMA32(pf11, wf2, o[1][2]);
        o[0][3] = MFMA32(pf01, wf3, o[0][3]);
        o[1][3] = MFMA32(pf11, wf3, o[1][3]);
        SGB(0x8, 8);
    };

    for (int it2 = 0; it2 < 64; it2++) {
        body(2 * it2, 0);
        body(2 * it2 + 1, 1);
    }

    // epilogue: finish l reduction (cross-quad) once, convert to C layout, write
    for (int mt = 0; mt < 2; mt++) {
        float l = l_i[mt];
        l += __shfl_xor(l, 16);
        l += __shfl_xor(l, 32);          // full row sum for q=l16, replicated across quads
        float inv = 1.0f / l;
        float invC[4];
        for (int r = 0; r < 4; r++) invC[r] = __shfl(inv, quad * 4 + r);   // q = quad*4+r
        for (int nt = 0; nt < 4; nt++)
            for (int r = 0; r < 4; r++) {
                int sg = q0g + mq + mt * 16 + quad * 4 + r;
                int n = h * 64 + nt * 16 + l16;
                Attn[((size_t)(b * 8192 + sg)) * 512 + n] = f2bf(o[mt][nt][r] * invC[r]);
            }
    }
}

// ---------------- output projection: Out = Attn @ Wo + b, fp32 ----------------
__global__ __launch_bounds__(256) void k_gemm_out(const u16* __restrict__ A, const u16* __restrict__ Wot,
                                                  const float* __restrict__ bias, float* __restrict__ Out) {
    __shared__ u16 As[128][40];
    __shared__ u16 Bs[128][40];
    const int t = threadIdx.x;
    const int wave = t >> 6, lane = t & 63, quad = lane >> 4, l16 = lane & 15;
    const int wm = (wave >> 1) * 64, wn = (wave & 1) * 64;
    const int m0 = blockIdx.x * 128, n0 = blockIdx.y * 128;
    const f32x4 fz = {0.f, 0.f, 0.f, 0.f};
    f32x4 acc[4][4];
    for (int i = 0; i < 4; i++) for (int j = 0; j < 4; j++) acc[i][j] = fz;
    for (int k0 = 0; k0 < 512; k0 += 32) {
        __syncthreads();
        for (int i = 0; i < 2; i++) {
            int id = t + i * 256;
            int row = id >> 2, c8 = (id & 3) * 8;
            *(uint4*)&As[row][c8] = *(const uint4*)(A + (size_t)(m0 + row) * 512 + k0 + c8);
            *(uint4*)&Bs[row][c8] = *(const uint4*)(Wot + (size_t)(n0 + row) * 512 + k0 + c8);
        }
        __syncthreads();
        short8 af[4], bf[4];
        for (int mt = 0; mt < 4; mt++) af[mt] = *(const short8*)&As[wm + mt * 16 + l16][quad * 8];
        for (int nt = 0; nt < 4; nt++) bf[nt] = *(const short8*)&Bs[wn + nt * 16 + l16][quad * 8];
        for (int mt = 0; mt < 4; mt++)
            for (int nt = 0; nt < 4; nt++)
                acc[mt][nt] = MFMA32(af[mt], bf[nt], acc[mt][nt]);
    }
    float bv[4];
    for (int nt = 0; nt < 4; nt++) bv[nt] = bias[n0 + wn + nt * 16 + l16];
    for (int mt = 0; mt < 4; mt++)
        for (int nt = 0; nt < 4; nt++)
            for (int r = 0; r < 4; r++) {
                int m = m0 + wm + mt * 16 + quad * 4 + r;
                int n = n0 + wn + nt * 16 + l16;
                Out[(size_t)m * 512 + n] = acc[mt][nt][r] + bv[nt];
            }
}

extern "C" void kernel_launch(void* const* d_in, const int* in_sizes, int n_in,
                              void* d_out, int out_size, void* d_ws, size_t ws_size,
                              hipStream_t stream) {
    const float* X   = (const float*)d_in[0];
    const float* w_q = (const float*)d_in[1];
    const float* w_k = (const float*)d_in[2];
    const float* w_v = (const float*)d_in[3];
    const float* w_o = (const float*)d_in[4];
    const float* b_o = (const float*)d_in[5];
    float* Out = (float*)d_out;

    char* ws = (char*)d_ws;
    u16* Xb   = (u16*)(ws);                 // 16 MiB  (reused as Attn after QKV GEMM)
    u16* Wt   = (u16*)(ws + 16777216);      //  2 MiB
    u16* Qd   = (u16*)(ws + 18874368);      // 16 MiB  (bh,s,d)
    u16* Kd   = (u16*)(ws + 35651584);      // 16 MiB  (bh,s,d)
    u16* Vd   = (u16*)(ws + 52428800);      // 16 MiB  (bh,s,d)
    u16* Vtd  = (u16*)(ws + 69206016);      // 16 MiB  (bh,d,s)
    u16* Attn = Xb;

    hipLaunchKernelGGL(k_convert_x, dim3(8192), dim3(256), 0, stream, X, Xb);
    hipLaunchKernelGGL(k_convert_w, dim3(8, 8, 4), dim3(256), 0, stream, w_q, w_k, w_v, w_o, Wt);
    hipLaunchKernelGGL(k_gemm_qkv, dim3(128, 4, 3), dim3(256), 0, stream, Xb, Wt, Qd, Kd, Vd);
    hipLaunchKernelGGL(k_transpose_v, dim3(128, 16), dim3(256), 0, stream, Vd, Vtd);
    hipLaunchKernelGGL(k_flash, dim3(32, 16), dim3(512), 0, stream, Qd, Kd, Vtd, Attn);
    hipLaunchKernelGGL(k_gemm_out, dim3(128, 4), dim3(256), 0, stream, Attn, Wt + 3 * 262144, b_o, Out);
}

// Round 7
// 407.633 us; speedup vs baseline: 1.0849x; 1.0849x over previous
//
#include <hip/hip_runtime.h>
#include <stdint.h>

typedef unsigned short u16;
typedef __attribute__((ext_vector_type(8))) short short8;
typedef __attribute__((ext_vector_type(4))) float f32x4;
typedef __attribute__((ext_vector_type(16))) float f32x16;

#define MFMA32(a, b, c) __builtin_amdgcn_mfma_f32_16x16x32_bf16(a, b, c, 0, 0, 0)
#define MFMA3232(a, b, c) __builtin_amdgcn_mfma_f32_32x32x16_bf16(a, b, c, 0, 0, 0)

#if __has_builtin(__builtin_amdgcn_exp2f)
#define EXP2F(x) __builtin_amdgcn_exp2f(x)
#else
#define EXP2F(x) exp2f(x)   // host-pass fallback only
#endif

// async global->LDS DMA, 16B per lane; dst must be base+lane*16 contiguous per wave
#define ASYNC16(G, L)                                                            \
    __builtin_amdgcn_global_load_lds((const __attribute__((address_space(1))) void*)(const void*)(G), \
                                     (__attribute__((address_space(3))) void*)(void*)(L), 16, 0, 0)

__device__ __forceinline__ u16 f2bf(float f) {
    union { float f; uint32_t u; } c; c.f = f;
    uint32_t r = (c.u + 0x7fffu + ((c.u >> 16) & 1u)) >> 16;
    return (u16)r;
}

// ---------------- convert + transpose the 4 weight matrices -> W^T bf16 (n-major) ----------------
__global__ __launch_bounds__(256) void k_convert_w(const float* __restrict__ W0, const float* __restrict__ W1,
                                                   const float* __restrict__ W2, const float* __restrict__ W3,
                                                   u16* __restrict__ Wt) {
    __shared__ u16 T[64][72];
    const float* W = (blockIdx.z == 0) ? W0 : (blockIdx.z == 1) ? W1 : (blockIdx.z == 2) ? W2 : W3;
    int k0 = blockIdx.x * 64, n0 = blockIdx.y * 64;
    int t = threadIdx.x;
    for (int i = 0; i < 4; i++) {
        int id = t + i * 256;
        int row = id >> 4, c4 = (id & 15) * 4;
        float4 v = *(const float4*)(W + (size_t)(k0 + row) * 512 + n0 + c4);
        union { u16 s[4]; uint2 v; } u;
        u.s[0] = f2bf(v.x); u.s[1] = f2bf(v.y); u.s[2] = f2bf(v.z); u.s[3] = f2bf(v.w);
        *(uint2*)&T[row][c4] = u.v;
    }
    __syncthreads();
    u16* O = Wt + (size_t)blockIdx.z * 512 * 512;
    for (int i = 0; i < 2; i++) {
        int id = t + i * 256;
        int row = id >> 3, c8 = (id & 7) * 8;
        union { u16 s[8]; uint4 v; } tmp;
        for (int j = 0; j < 8; j++) tmp.s[j] = T[c8 + j][row];
        *(uint4*)(O + (size_t)(n0 + row) * 512 + k0 + c8) = tmp.v;
    }
}

// ---------------- QKV projection GEMM (reads fp32 X directly; convert_x kernel dropped) ----------------
__global__ __launch_bounds__(256) void k_gemm_qkv(const float* __restrict__ X, const u16* __restrict__ Wt,
                                                  u16* __restrict__ Q, u16* __restrict__ K, u16* __restrict__ V) {
    __shared__ u16 As[128][40];
    __shared__ u16 Bs[128][40];
    const int t = threadIdx.x;
    const int wave = t >> 6, lane = t & 63, quad = lane >> 4, l16 = lane & 15;
    const int wm = (wave >> 1) * 64, wn = (wave & 1) * 64;
    const int m0 = blockIdx.x * 128, n0 = blockIdx.y * 128;
    const u16* Bt = Wt + (size_t)blockIdx.z * 262144;
    const f32x4 fz = {0.f, 0.f, 0.f, 0.f};
    f32x4 acc[4][4];
    for (int i = 0; i < 4; i++) for (int j = 0; j < 4; j++) acc[i][j] = fz;
    for (int k0 = 0; k0 < 512; k0 += 32) {
        __syncthreads();
        for (int i = 0; i < 2; i++) {
            int id = t + i * 256;
            int row = id >> 2, c8 = (id & 3) * 8;
            float4 xa = *(const float4*)(X + (size_t)(m0 + row) * 512 + k0 + c8);
            float4 xb = *(const float4*)(X + (size_t)(m0 + row) * 512 + k0 + c8 + 4);
            union { u16 s[8]; uint4 v; } ux;
            ux.s[0] = f2bf(xa.x); ux.s[1] = f2bf(xa.y); ux.s[2] = f2bf(xa.z); ux.s[3] = f2bf(xa.w);
            ux.s[4] = f2bf(xb.x); ux.s[5] = f2bf(xb.y); ux.s[6] = f2bf(xb.z); ux.s[7] = f2bf(xb.w);
            *(uint4*)&As[row][c8] = ux.v;
            *(uint4*)&Bs[row][c8] = *(const uint4*)(Bt + (size_t)(n0 + row) * 512 + k0 + c8);
        }
        __syncthreads();
        short8 af[4], bf[4];
        for (int mt = 0; mt < 4; mt++) af[mt] = *(const short8*)&As[wm + mt * 16 + l16][quad * 8];
        for (int nt = 0; nt < 4; nt++) bf[nt] = *(const short8*)&Bs[wn + nt * 16 + l16][quad * 8];
        for (int mt = 0; mt < 4; mt++)
            for (int nt = 0; nt < 4; nt++)
                acc[mt][nt] = MFMA32(af[mt], bf[nt], acc[mt][nt]);
    }
    const float scale = (blockIdx.z == 0) ? 0.18033688011112042f : 1.0f;   // (1/8)*log2(e) for Q
    u16* Out = (blockIdx.z == 0) ? Q : (blockIdx.z == 1) ? K : V;
    for (int mt = 0; mt < 4; mt++)
        for (int nt = 0; nt < 4; nt++)
            for (int r = 0; r < 4; r++) {
                int m = m0 + wm + mt * 16 + quad * 4 + r;
                int n = n0 + wn + nt * 16 + l16;
                int b = m >> 13, s = m & 8191, h = n >> 6, d = n & 63;
                Out[((size_t)((b * 8 + h) * 8192 + s)) * 64 + d] = f2bf(acc[mt][nt][r] * scale);
            }
}

// ---------------- V (bh,s,d) -> Vt (bh,d,s) ----------------
__global__ __launch_bounds__(256) void k_transpose_v(const u16* __restrict__ V, u16* __restrict__ Vt) {
    __shared__ u16 T[64][72];
    int s0 = blockIdx.x * 64, bh = blockIdx.y;
    int t = threadIdx.x;
    for (int i = 0; i < 2; i++) {
        int id = t + i * 256, row = id >> 3, c8 = (id & 7) * 8;
        *(uint4*)&T[row][c8] = *(const uint4*)(V + ((size_t)bh * 8192 + s0 + row) * 64 + c8);
    }
    __syncthreads();
    for (int i = 0; i < 2; i++) {
        int id = t + i * 256, row = id >> 3, c8 = (id & 7) * 8;
        union { u16 s[8]; uint4 v; } tmp;
        for (int j = 0; j < 8; j++) tmp.s[j] = T[c8 + j][row];
        *(uint4*)(Vt + ((size_t)bh * 64 + row) * 8192 + s0 + c8) = tmp.v;
    }
}

// ---------------- flash attention: 32x32x16 MFMA, S^T orientation, shift-free softmax ----------------
// R12: HALVE the MFMA instruction count. Evidence: six configs all pin MfmaUtil+VALUBusy at
// ~100-102% with the wall = MFMA-cycles + VALU-cycles SUMMED -> per-SIMD, matrix and vector
// work share the issue/execute resource (m114's overlap was CU-level across 4 SIMDs). The only
// remaining lever is fewer instruction-cycles: 16x16x32 (32 insts/body) -> 32x32x16 (16 insts,
// same FLOPs, ~20% fewer matrix pipe-cycles, half the issue slots).
//   Zero-shuffle P->PV handoff (same idea as the R0->R1 trick, re-derived for 32x32):
//   - K rows stored to LDS pre-permuted: LDS abstract row a holds K[p(a)], p = swap bits 2<->3.
//   - QK C-layout row=(reg&3)+8*(reg>>2)+4*hi then gives each lane physical keys
//     {0..7,16..23}+8*hi per 32-key tile, packed pairs in ascending order = EXACTLY the
//     A-fragment (row=lane&31=q, k=hi*8+j) of the PV 32x32x16 MFMA. No cross-lane ops.
//   - All LDS reads (rows lane&31 +32t, chunk (2g+hi)^(row&7)) are bank-uniform: 8 chunk-slots
//     x 8 lanes each -> 0 conflicts. DMA chunk-XOR swz = row&7 both K and V.
//   One q-row per lane -> single l_i; epilogue: 1 shfl_xor + 16 bpermutes (once).
// Outer structure = R1's proven schedule (512 thr, 2-buf, 1-ahead prefetch, __syncthreads).
__global__ __launch_bounds__(512, 4) void k_flash(const u16* __restrict__ Q, const u16* __restrict__ K,
                                                  const u16* __restrict__ Vt, u16* __restrict__ Attn) {
    __shared__ u16 KsAll[2][4096];   // [buf][abstract row a * 64 + chunk-swizzled d], a holds K[p(a)]
    __shared__ u16 VsAll[2][4096];   // [buf][d * 64 + chunk-swizzled keys]
    const int t = threadIdx.x;
    const int wave = t >> 6, lane = t & 63;
    const int l32 = lane & 31, hi = lane >> 5;
    const int s7 = l32 & 7;
    const int qblk = blockIdx.x, bh = blockIdx.y;
    const int b = bh >> 3, h = bh & 7;
    const int q0g = qblk * 256;
    const int mq = wave * 32;
    const u16* Qb = Q + ((size_t)bh * 8192 + q0g) * 64;
    const u16* Kb = K + (size_t)bh * 8192 * 64;
    const u16* Vb = Vt + (size_t)bh * 64 * 8192;

    // DMA: 512 threads x 16B = one full 8KB tile each for K and V; thread t <-> chunk t
    const int r0 = t >> 3;
    const int pr = (r0 & 3) | ((r0 & 4) << 1) | ((r0 & 8) >> 1) | (r0 & 48);  // swap bits 2,3 (key perm)
    const int x0K = ((t & 7) ^ (r0 & 7)) * 8;   // LDS row r0, slot t&7 holds data chunk (t&7)^(r0&7)
    const int x0V = ((t & 7) ^ (r0 & 7)) * 8;
    const u16* gK0 = Kb + pr * 64 + x0K;
    const u16* gV0 = Vb + (size_t)r0 * 8192 + x0V;
    u16* lK = &KsAll[0][0] + t * 8;
    u16* lV = &VsAll[0][0] + t * 8;

    auto prefetch = [&](int it, int buf) {
        ASYNC16(gK0 + it * 4096, lK + buf * 4096);
        ASYNC16(gV0 + it * 64,   lV + buf * 4096);
    };

    // Q fragments (B-operand): col=lane&31=q, elems k = d = g*16 + hi*8 + j. Loop-invariant.
    short8 qf[4];
    for (int g = 0; g < 4; g++)
        qf[g] = *(const short8*)(Qb + (size_t)(mq + l32) * 64 + g * 16 + hi * 8);

    const f32x16 fz16 = {};
    f32x16 o0 = {}, o1 = {};
    float l_i = 0.f;

    prefetch(0, 0);

    auto body = [&](int it, int buf) {
        __syncthreads();                       // drains prefetch(it) (issued one body ago)
        if (it != 127) prefetch(it + 1, buf ^ 1);
        const u16* KsB = &KsAll[buf][0];
        const u16* VsB = &VsAll[buf][0];

        // QK: S^T as two 32x32 tiles (key-halves), K-chained over 4 d-groups.
        // A-frag: row = lane&31 (abstract key row), elems = d chunk (2g+hi), swz ^(row&7).
        const u16* K0 = KsB + l32 * 64;
        const u16* K1 = K0 + 2048;             // rows +32 (tile 1)
        f32x16 s0, s1;
        s0 = MFMA3232(*(const short8*)(K0 + ((0 + hi) ^ s7) * 8), qf[0], fz16);
        s0 = MFMA3232(*(const short8*)(K0 + ((2 + hi) ^ s7) * 8), qf[1], s0);
        s0 = MFMA3232(*(const short8*)(K0 + ((4 + hi) ^ s7) * 8), qf[2], s0);
        s0 = MFMA3232(*(const short8*)(K0 + ((6 + hi) ^ s7) * 8), qf[3], s0);
        s1 = MFMA3232(*(const short8*)(K1 + ((0 + hi) ^ s7) * 8), qf[0], fz16);
        s1 = MFMA3232(*(const short8*)(K1 + ((2 + hi) ^ s7) * 8), qf[1], s1);
        s1 = MFMA3232(*(const short8*)(K1 + ((4 + hi) ^ s7) * 8), qf[2], s1);
        s1 = MFMA3232(*(const short8*)(K1 + ((6 + hi) ^ s7) * 8), qf[3], s1);

        // exp2 + pack. Word w[t][j]: physical keys {2j,2j+1}+8hi (j<4) / {2j+8,2j+9}+8hi (j>=4)
        // of tile t -- ascending, exactly the PV A-fragment order.
        union fu { float f; uint32_t u; };
        uint32_t w[2][8];
#pragma unroll
        for (int j = 0; j < 8; j++) {
            fu a, c; a.f = EXP2F(s0[2 * j]); c.f = EXP2F(s0[2 * j + 1]);
            l_i += a.f + c.f;
            w[0][j] = __builtin_amdgcn_perm(c.u, a.u, 0x07060302);
        }
#pragma unroll
        for (int j = 0; j < 8; j++) {
            fu a, c; a.f = EXP2F(s1[2 * j]); c.f = EXP2F(s1[2 * j + 1]);
            l_i += a.f + c.f;
            w[1][j] = __builtin_amdgcn_perm(c.u, a.u, 0x07060302);
        }

        // PV: O[32q x 64d] = two 32x32 d-tiles, K-chained over 4 key-groups f.
        // A-frag f = words w[f>>1][4*(f&1)..+3] (keys f*16+hi*8+{0..7});
        // B-frag: col=lane&31=d, elems = keys chunk (2f+hi), swz ^(d&7).
        const u16* V0 = VsB + l32 * 64;
        const u16* V1 = V0 + 2048;             // d +32
#pragma unroll
        for (int f = 0; f < 4; f++) {
            union { uint32_t u[4]; short8 s; } pk;
            pk.u[0] = w[f >> 1][4 * (f & 1) + 0];
            pk.u[1] = w[f >> 1][4 * (f & 1) + 1];
            pk.u[2] = w[f >> 1][4 * (f & 1) + 2];
            pk.u[3] = w[f >> 1][4 * (f & 1) + 3];
            short8 va = *(const short8*)(V0 + ((2 * f + hi) ^ s7) * 8);
            short8 vb = *(const short8*)(V1 + ((2 * f + hi) ^ s7) * 8);
            o0 = MFMA3232(pk.s, va, o0);
            o1 = MFMA3232(pk.s, vb, o1);
        }
    };

    for (int it2 = 0; it2 < 64; it2++) {
        body(2 * it2, 0);
        body(2 * it2 + 1, 1);
    }

    // epilogue: l covers this lane's half of the keys; partner (lane^32) has the other half.
    l_i += __shfl_xor(l_i, 32);
    float inv = 1.0f / l_i;                    // inv for q = l32 (both hi lanes hold it)
#pragma unroll
    for (int reg = 0; reg < 16; reg++) {
        int qrow = (reg & 3) + 8 * (reg >> 2) + 4 * hi;
        float iv = __shfl(inv, qrow);          // lane qrow (hi=0) holds inv for q=qrow
        int sg = q0g + mq + qrow;
        size_t base = ((size_t)(b * 8192 + sg)) * 512 + h * 64;
        Attn[base + l32]      = f2bf(o0[reg] * iv);
        Attn[base + 32 + l32] = f2bf(o1[reg] * iv);
    }
}

// ---------------- output projection: Out = Attn @ Wo + b, fp32 ----------------
__global__ __launch_bounds__(256) void k_gemm_out(const u16* __restrict__ A, const u16* __restrict__ Wot,
                                                  const float* __restrict__ bias, float* __restrict__ Out) {
    __shared__ u16 As[128][40];
    __shared__ u16 Bs[128][40];
    const int t = threadIdx.x;
    const int wave = t >> 6, lane = t & 63, quad = lane >> 4, l16 = lane & 15;
    const int wm = (wave >> 1) * 64, wn = (wave & 1) * 64;
    const int m0 = blockIdx.x * 128, n0 = blockIdx.y * 128;
    const f32x4 fz = {0.f, 0.f, 0.f, 0.f};
    f32x4 acc[4][4];
    for (int i = 0; i < 4; i++) for (int j = 0; j < 4; j++) acc[i][j] = fz;
    for (int k0 = 0; k0 < 512; k0 += 32) {
        __syncthreads();
        for (int i = 0; i < 2; i++) {
            int id = t + i * 256;
            int row = id >> 2, c8 = (id & 3) * 8;
            *(uint4*)&As[row][c8] = *(const uint4*)(A + (size_t)(m0 + row) * 512 + k0 + c8);
            *(uint4*)&Bs[row][c8] = *(const uint4*)(Wot + (size_t)(n0 + row) * 512 + k0 + c8);
        }
        __syncthreads();
        short8 af[4], bf[4];
        for (int mt = 0; mt < 4; mt++) af[mt] = *(const short8*)&As[wm + mt * 16 + l16][quad * 8];
        for (int nt = 0; nt < 4; nt++) bf[nt] = *(const short8*)&Bs[wn + nt * 16 + l16][quad * 8];
        for (int mt = 0; mt < 4; mt++)
            for (int nt = 0; nt < 4; nt++)
                acc[mt][nt] = MFMA32(af[mt], bf[nt], acc[mt][nt]);
    }
    float bv[4];
    for (int nt = 0; nt < 4; nt++) bv[nt] = bias[n0 + wn + nt * 16 + l16];
    for (int mt = 0; mt < 4; mt++)
        for (int nt = 0; nt < 4; nt++)
            for (int r = 0; r < 4; r++) {
                int m = m0 + wm + mt * 16 + quad * 4 + r;
                int n = n0 + wn + nt * 16 + l16;
                Out[(size_t)m * 512 + n] = acc[mt][nt][r] + bv[nt];
            }
}

extern "C" void kernel_launch(void* const* d_in, const int* in_sizes, int n_in,
                              void* d_out, int out_size, void* d_ws, size_t ws_size,
                              hipStream_t stream) {
    const float* X   = (const float*)d_in[0];
    const float* w_q = (const float*)d_in[1];
    const float* w_k = (const float*)d_in[2];
    const float* w_v = (const float*)d_in[3];
    const float* w_o = (const float*)d_in[4];
    const float* b_o = (const float*)d_in[5];
    float* Out = (float*)d_out;

    char* ws = (char*)d_ws;
    u16* Attn = (u16*)(ws);                 // 16 MiB
    u16* Wt   = (u16*)(ws + 16777216);      //  2 MiB
    u16* Qd   = (u16*)(ws + 18874368);      // 16 MiB  (bh,s,d)
    u16* Kd   = (u16*)(ws + 35651584);      // 16 MiB  (bh,s,d)
    u16* Vd   = (u16*)(ws + 52428800);      // 16 MiB  (bh,s,d)
    u16* Vtd  = (u16*)(ws + 69206016);      // 16 MiB  (bh,d,s)

    hipLaunchKernelGGL(k_convert_w, dim3(8, 8, 4), dim3(256), 0, stream, w_q, w_k, w_v, w_o, Wt);
    hipLaunchKernelGGL(k_gemm_qkv, dim3(128, 4, 3), dim3(256), 0, stream, X, Wt, Qd, Kd, Vd);
    hipLaunchKernelGGL(k_transpose_v, dim3(128, 16), dim3(256), 0, stream, Vd, Vtd);
    hipLaunchKernelGGL(k_flash, dim3(32, 16), dim3(512), 0, stream, Qd, Kd, Vtd, Attn);
    hipLaunchKernelGGL(k_gemm_out, dim3(128, 4), dim3(256), 0, stream, Attn, Wt + 3 * 262144, b_o, Out);
}